// Round 13
// baseline (12385.091 us; speedup 1.0000x reference)
//
#include <hip/hip_runtime.h>
#include <math.h>

#define TPB 1024
#define NBLK 256
#define NBATCH 32
#define NT 64
#define NH 512
#define NM 128
#define NR 4
#define NW 64
#define NI 768          // controller input size (H + R*W)
#define NXI 471         // interface vector size
#define NG 2048         // gate rows
#define EPSF 1e-6f
#define MS 65           // mem row stride (+1 pad)

// roles: [0,32) state | [32,160) gates(128) | [160,192) xi(32) | [192,256) out(64)

// ws layout (float offsets). pub* parity double-buffered.
#define WS_LINK  0                                 // [32][128*128]
#define WS_PUBH  (WS_LINK + NBATCH*NM*NM)          // [2][32][512]
#define WS_PUBRV (WS_PUBH + 2*NBATCH*NH)           // [2][32][256]
#define WS_PUBG  (WS_PUBRV + 2*NBATCH*NR*NW)       // [2][32][2048]
#define WS_PUBXI (WS_PUBG + 2*NBATCH*NG)           // [2][32][480]
#define WS_CNT   (WS_PUBXI + 2*NBATCH*480)         // 288 x 16-uint padded counters
// counter sub-offsets (in uints, each slot 16 uints = 64 B)
#define C_SH  0                  // 32: state h published   (value t+2)
#define C_SR  (32*16)            // 32: state rv published  (value t+2)
#define C_G   (64*16)            // 128: gates(t) published (value t+1)
#define C_X   (192*16)           // 32: xi(t) published     (value t+1)
#define C_O   (224*16)           // 64: out(t) done         (value t+1)
#define C_TOT (288*16)

__device__ __forceinline__ float sigm(float x){ return 1.0f/(1.0f+expf(-x)); }
__device__ __forceinline__ float sftp(float x){ return fmaxf(x,0.0f)+log1pf(expf(-fabsf(x))); }
__device__ __forceinline__ float dot4(float4 a, float4 b){
    return a.x*b.x + a.y*b.y + a.z*b.z + a.w*b.w;
}
__device__ __forceinline__ float wave_red(float v){
    #pragma unroll
    for (int o = 32; o > 0; o >>= 1) v += __shfl_down(v, o);
    return v;
}
// LLC-coherent accessors (bypass L2, no invalidates) — proven r7-r11
__device__ __forceinline__ void cstore(float* p, float v){
    __hip_atomic_store(p, v, __ATOMIC_RELAXED, __HIP_MEMORY_SCOPE_AGENT);
}
__device__ __forceinline__ float cload(const float* p){
    return __hip_atomic_load(p, __ATOMIC_RELAXED, __HIP_MEMORY_SCOPE_AGENT);
}
// parallel wait: thread i polls counter i (own cacheline) — no contention
__device__ __forceinline__ void wait_many(unsigned int* base, int n,
                                          unsigned int target, int tid){
    if (tid < n) {
        unsigned int* p = base + tid*16;
        while (__hip_atomic_load(p, __ATOMIC_RELAXED,
                                 __HIP_MEMORY_SCOPE_AGENT) < target)
            __builtin_amdgcn_s_sleep(1);
    }
    __syncthreads();
}
// release-store own counter (orders prior sc1 data stores; no RMW)
__device__ __forceinline__ void post(unsigned int* p, unsigned int val, int tid){
    __syncthreads();
    if (tid == 0)
        __hip_atomic_store(p, val, __ATOMIC_RELEASE, __HIP_MEMORY_SCOPE_AGENT);
}

__global__ void dnc_zero(float* ws){
    unsigned int* z = (unsigned int*)(ws + WS_CNT);
    for (int e = threadIdx.x; e < C_TOT; e += 1024) z[e] = 0u;
}

// ---- pooled LDS (floats); shared by all roles ----
#define O_MEM 0
#define O_H   8320
#define O_C   8832
#define O_RW  9344
#define O_WWO 9856
#define O_WWN 9984
#define O_USG 10112
#define O_PRC 10240
#define O_XI  10368
#define O_KEY 10840
#define O_WK  11096
#define O_ER  11160
#define O_WV  11224
#define O_RS  11288
#define O_FG  11292
#define O_MD  11296
#define O_NK  11308
#define O_SC  11312
#define O_NMO 11320
#define O_NMN 11448
#define O_WCW 11576
#define O_UU  11704
#define O_SU  11832
#define O_CUM 11960
#define O_RNK 12088
#define O_CCW 12216
#define O_FWD 12728
#define O_RV  13240
#define O_RED 13496
#define S_SZ  13504

__global__ __launch_bounds__(TPB) void dnc_pipe(
    const float* __restrict__ x, const float* __restrict__ W_ih,
    const float* __restrict__ W_hh, const float* __restrict__ b_ih,
    const float* __restrict__ b_hh, const float* __restrict__ W_xi,
    const float* __restrict__ b_xi, const float* __restrict__ W_o,
    const float* __restrict__ b_o, float* __restrict__ out,
    float* __restrict__ ws)
{
    __shared__ __align__(16) float S[S_SZ];

    const int tid = threadIdx.x;
    const int wv  = tid >> 6;
    const int l   = tid & 63;
    const int bid = blockIdx.x;

    float* __restrict__ pubH  = ws + WS_PUBH;
    float* __restrict__ pubRV = ws + WS_PUBRV;
    float* __restrict__ pubG  = ws + WS_PUBG;
    float* __restrict__ pubXI = ws + WS_PUBXI;
    unsigned int* __restrict__ CNT = (unsigned int*)(ws + WS_CNT);
    unsigned int* cSH = CNT + C_SH;
    unsigned int* cSR = CNT + C_SR;
    unsigned int* cG  = CNT + C_G;
    unsigned int* cX  = CNT + C_X;
    unsigned int* cO  = CNT + C_O;

    if (bid < NBATCH) {
        // ========================= STATE block =========================
        const int b = bid;
        float* __restrict__ lk = ws + WS_LINK + (size_t)b*NM*NM;
        float* mem = S+O_MEM;  float* hS = S+O_H;   float* cS = S+O_C;
        float* rwS = S+O_RW;   float* wwO = S+O_WWO; float* wwN = S+O_WWN;
        float* usg = S+O_USG;  float* prc = S+O_PRC; float* xiS = S+O_XI;
        float* keys = S+O_KEY; float* wkey = S+O_WK; float* ers = S+O_ER;
        float* wvec = S+O_WV;  float* rstr = S+O_RS; float* fgte = S+O_FG;
        float* modes = S+O_MD; float* nkey = S+O_NK; float* sc = S+O_SC;
        float* nmo = S+O_NMO;  float* nmn = S+O_NMN; float* wcw = S+O_WCW;
        float* uu = S+O_UU;    float* su = S+O_SU;   float* cum = S+O_CUM;
        int*   rnk = (int*)(S+O_RNK);
        float* ccw = S+O_CCW;  float* fwdT = S+O_FWD; float* rv = S+O_RV;
        float* red = S+O_RED;

        for (int e = tid; e < NM*NM; e += TPB) lk[e] = 0.0f;
        for (int e = tid; e < NM*NW; e += TPB) mem[(e>>6)*MS + (e&63)] = EPSF;
        for (int e = tid; e < NH; e += TPB){ hS[e]=0.0f; cS[e]=0.0f; }
        for (int e = tid; e < NR*NM; e += TPB) rwS[e]=0.0f;
        for (int e = tid; e < NM; e += TPB){ wwO[e]=0.0f; usg[e]=0.0f; prc[e]=0.0f; }
        // publish h_{-1}=0, rv_{-1}=0 into parity 1
        if (tid < NH)    cstore(&pubH[(size_t)1*NBATCH*NH + b*NH + tid], 0.0f);
        if (tid < NR*NW) cstore(&pubRV[(size_t)1*NBATCH*NR*NW + b*NR*NW + tid], 0.0f);
        post(&cSH[b*16], 1u, tid);
        post(&cSR[b*16], 1u, tid);

        for (int t = 0; t < NT; ++t) {
            const int par = t & 1;
            // gates(t) ready (128 parallel polls)
            wait_many(cG, 128, (unsigned)(t+1), tid);
            {
                const float* gb = pubG + ((size_t)par*NBATCH + b)*NG;
                if (tid < NH) {
                    float ig = sigm(cload(&gb[tid]));
                    float fg = sigm(cload(&gb[NH + tid]));
                    float gg = tanhf(cload(&gb[2*NH + tid]));
                    float og = sigm(cload(&gb[3*NH + tid]));
                    float c = fg*cS[tid] + ig*gg;
                    cS[tid] = c;
                    hS[tid] = og*tanhf(c);
                }
            }
            __syncthreads();
            // out(t-2) must be done before overwriting its h/rv parity
            if (t >= 2) wait_many(cO, 64, (unsigned)(t-1), tid);
            if (tid < NH) cstore(&pubH[(size_t)par*NBATCH*NH + b*NH + tid], hS[tid]);
            post(&cSH[b*16], (unsigned)(t+2), tid);

            // nmo (old-mem norms) — no xi dependency; overlaps xi compute
            #pragma unroll
            for (int ri = 0; ri < 8; ++ri) {
                int row = wv*8 + ri;
                float v = mem[row*MS + l];
                float s2 = wave_red(v*v);
                if (l == 0) nmo[row] = sqrtf(s2);
            }
            __syncthreads();

            // xi(t) ready
            wait_many(cX, 32, (unsigned)(t+1), tid);
            if (tid < NXI) xiS[tid] = cload(&pubXI[(size_t)par*NBATCH*480 + b*480 + tid]);
            __syncthreads();

            // E1: unpack interface
            if (tid < 256)       keys[tid] = tanhf(xiS[tid]);
            else if (tid < 260)  rstr[tid-256] = sftp(xiS[tid]);
            else if (tid < 324)  wkey[tid-260] = tanhf(xiS[tid]);
            else if (tid == 324) sc[0] = sftp(xiS[324]);
            else if (tid < 389)  ers[tid-325] = sigm(xiS[tid]);
            else if (tid < 453)  wvec[tid-389] = tanhf(xiS[tid]);
            else if (tid < 457)  fgte[tid-453] = sigm(xiS[tid]);
            else if (tid == 457) sc[1] = sigm(xiS[457]);
            else if (tid == 458) sc[2] = sigm(xiS[458]);
            else if (tid < 463) {
                int r = tid - 459;
                float a0=xiS[459+3*r], a1=xiS[460+3*r], a2=xiS[461+3*r];
                float mx = fmaxf(a0, fmaxf(a1, a2));
                float e0=expf(a0-mx), e1=expf(a1-mx), e2=expf(a2-mx);
                float si = 1.0f/(e0+e1+e2);
                modes[3*r]=e0*si; modes[3*r+1]=e1*si; modes[3*r+2]=e2*si;
            }
            __syncthreads();

            // E2a: key norms (keys from E1)
            if (tid < NR) {
                float ssum = 0.0f;
                for (int w = 0; w < NW; ++w) { float v = keys[tid*NW+w]; ssum += v*v; }
                nkey[tid] = sqrtf(ssum);
            } else if (tid == NR) {
                float ssum = 0.0f;
                for (int w = 0; w < NW; ++w) { float v = wkey[w]; ssum += v*v; }
                sc[3] = sqrtf(ssum);
            }
            // E2b: usage update + uu (fused)
            if (tid >= 64 && tid < 64+NM) {
                int m = tid - 64;
                float u = usg[m];
                u = u + (1.0f - u)*wwO[m];
                float psi = 1.0f;
                #pragma unroll
                for (int r = 0; r < NR; ++r) psi *= (1.0f - fgte[r]*rwS[r*NM+m]);
                u *= psi;
                usg[m] = u;
                uu[m] = 5e-6f + (1.0f - 5e-6f)*u;
            }
            __syncthreads();

            // F1: write-content logits
            if (tid < NM) {
                float d = 0.0f;
                for (int w = 0; w < NW; ++w) d += wkey[w]*mem[tid*MS+w];
                wcw[tid] = d/(sc[3]*nmo[tid] + EPSF) * sc[0];
            }
            __syncthreads();
            // F2: softmax over 128
            if (tid < 64) {
                float v = fmaxf(wcw[tid], wcw[tid+64]);
                #pragma unroll
                for (int o = 32; o > 0; o >>= 1) v = fmaxf(v, __shfl_down(v, o));
                if (tid == 0) red[0] = v;
            }
            __syncthreads();
            if (tid < NM) wcw[tid] = expf(wcw[tid] - red[0]);
            __syncthreads();
            if (tid < 64) {
                float v = wave_red(wcw[tid] + wcw[tid+64]);
                if (tid == 0) red[0] = 1.0f/v;
            }
            __syncthreads();
            if (tid < NM) wcw[tid] *= red[0];
            __syncthreads();

            // G2: stable rank
            if (tid < NM) {
                float um = uu[tid]; int rk = 0;
                for (int j = 0; j < NM; ++j) {
                    float uj = uu[j];
                    rk += (uj < um) || (uj == um && j < tid);
                }
                rnk[tid] = rk;
                su[rk] = um;
            }
            __syncthreads();
            // G3: product scan (wave 0)
            if (tid < 64) {
                float a = su[tid], bb = su[64+tid];
                #pragma unroll
                for (int o = 1; o < 64; o <<= 1) {
                    float ta = __shfl_up(a, o);
                    float tb = __shfl_up(bb, o);
                    if (tid >= o) { a *= ta; bb *= tb; }
                }
                float P0 = __shfl(a, 63);
                cum[tid] = a;
                cum[64+tid] = P0*bb;
            }
            __syncthreads();
            // G4: alloc + write weighting
            if (tid < NM) {
                int rk = rnk[tid];
                float excl = (rk == 0) ? 1.0f : cum[rk-1];
                float al = (1.0f - uu[tid])*excl;
                wwN[tid] = sc[2]*(sc[1]*al + (1.0f - sc[1])*wcw[tid]);
            }
            __syncthreads();
            // G5: sum(wwN)
            if (tid < 64) {
                float v = wave_red(wwN[tid] + wwN[tid+64]);
                if (tid == 0) sc[4] = v;
            }
            __syncthreads();

            // H (fused): mem erase/write + new norms (wave-per-row) + link
            #pragma unroll
            for (int ri = 0; ri < 8; ++ri) {
                int row = wv*8 + ri;
                float wm = wwN[row];
                float v = mem[row*MS + l];
                float nv = v*(1.0f - wm*ers[l]) + wm*wvec[l];
                mem[row*MS + l] = nv;
                float s2 = wave_red(nv*nv);
                if (l == 0) nmn[row] = sqrtf(s2);
            }
            for (int e = tid; e < NM*NM; e += TPB) {
                int i = e >> 7, j = e & 127;
                float nl = (i == j) ? 0.0f
                         : (1.0f - wwN[i] - wwN[j])*lk[e] + wwN[i]*prc[j];
                lk[e] = nl;
            }
            __syncthreads();
            // H3: precedence
            if (tid < NM) prc[tid] = (1.0f - sc[4])*prc[tid] + wwN[tid];
            __syncthreads();

            // I: read-content logits + per-r softmax
            if (tid < NR*NM) {
                int r = tid >> 7, m = tid & 127;
                float d = 0.0f;
                for (int w = 0; w < NW; ++w) d += keys[r*NW+w]*mem[m*MS+w];
                ccw[tid] = d/(nkey[r]*nmn[m] + EPSF) * rstr[r];
            }
            __syncthreads();
            if (tid < 256) {
                int r = tid >> 6, ll = tid & 63;
                float v = fmaxf(ccw[r*NM+ll], ccw[r*NM+ll+64]);
                #pragma unroll
                for (int o = 32; o > 0; o >>= 1) v = fmaxf(v, __shfl_down(v, o));
                if (ll == 0) red[r] = v;
            }
            __syncthreads();
            if (tid < NR*NM) ccw[tid] = expf(ccw[tid] - red[tid>>7]);
            __syncthreads();
            if (tid < 256) {
                int r = tid >> 6, ll = tid & 63;
                float v = wave_red(ccw[r*NM+ll] + ccw[r*NM+ll+64]);
                if (ll == 0) red[4+r] = 1.0f/v;
            }
            __syncthreads();
            if (tid < NR*NM) ccw[tid] *= red[4+(tid>>7)];
            __syncthreads();

            // J1: fwd[r][m]
            {
                const int p0 = wv*32;
                for (int i = 0; i < 32; ++i) {
                    const int p = p0 + i, r = p >> 7, m = p & 127;
                    float partial = lk[m*NM + l]*rwS[r*NM + l]
                                  + lk[m*NM + 64 + l]*rwS[r*NM + 64 + l];
                    partial = wave_red(partial);
                    if (l == 0) fwdT[p] = partial;
                }
            }
            __syncthreads();
            // J2: bwd + mode mix
            float rwnew = 0.0f;
            if (tid < NR*NM) {
                int r = tid >> 7, m = tid & 127;
                float bw = 0.0f;
                for (int i = 0; i < NM; ++i) bw += lk[i*NM+m]*rwS[r*NM+i];
                rwnew = modes[3*r]*bw + modes[3*r+1]*fwdT[tid] + modes[3*r+2]*ccw[tid];
            }
            __syncthreads();
            if (tid < NR*NM) rwS[tid] = rwnew;
            __syncthreads();

            // K: read vectors + publish rv
            if (tid < NR*NW) {
                int r = tid >> 6, w = tid & 63;
                float ssum = 0.0f;
                for (int m = 0; m < NM; ++m) ssum += rwS[r*NM+m]*mem[m*MS+w];
                rv[tid] = ssum;
                cstore(&pubRV[(size_t)par*NBATCH*NR*NW + b*NR*NW + tid], ssum);
            }
            post(&cSR[b*16], (unsigned)(t+2), tid);

            if (tid < NM) wwO[tid] = wwN[tid];
            __syncthreads();
        }
    } else if (bid < 32 + 128) {
        // ========================= GATES block (16 rows) ====================
        const int g = bid - 32;
        const int r = g*16 + wv;
        const float4* WA = (const float4*)(W_ih + (size_t)r*NI);
        float4 wx0 = WA[l], wx1 = WA[l+64], wrv = WA[128+l];
        const float4* WB = (const float4*)(W_hh + (size_t)r*NH);
        float4 wh0 = WB[l], wh1 = WB[l+64];
        const float bias = b_ih[r] + b_hh[r];
        float acc[32];

        for (int t = 0; t < NT; ++t) {
            const int par = t & 1, parp = (t+1) & 1;   // parp = parity of t-1
            // EARLY: x(t) + h(t-1) — overlaps state machinery of step t-1
            wait_many(cSH, 32, (unsigned)(t+1), tid);
            const float* hIn = pubH + (size_t)parp*NBATCH*NH;
            #pragma unroll
            for (int p = 0; p < 4; ++p) {
                const int b0 = p*8;
                // x: 8 batches x 512 floats -> S[0..4095]
                #pragma unroll
                for (int it = 0; it < 4; ++it) { int idx = tid + it*1024;
                    int bi = idx >> 9, k = idx & 511;
                    S[bi*512 + k] = x[((size_t)(b0+bi)*NT + t)*NH + k]; }
                // h: 8 batches x 512 floats -> S[4096..8191]
                #pragma unroll
                for (int it = 0; it < 4; ++it) { int idx = tid + it*1024;
                    int bi = idx >> 9, k = idx & 511;
                    S[4096 + bi*512 + k] = cload(&hIn[(b0+bi)*NH + k]); }
                __syncthreads();
                #pragma unroll
                for (int bi = 0; bi < 8; ++bi) {
                    const float4* X4 = (const float4*)(S + bi*512);
                    const float4* H4 = (const float4*)(S + 4096 + bi*512);
                    acc[b0+bi] = dot4(wx0, X4[l]) + dot4(wx1, X4[l+64])
                               + dot4(wh0, H4[l]) + dot4(wh1, H4[l+64]);
                }
                __syncthreads();
            }
            // LATE: rv(t-1) — the only critical-path part
            wait_many(cSR, 32, (unsigned)(t+1), tid);
            const float* rIn = pubRV + (size_t)parp*NBATCH*NR*NW;
            #pragma unroll
            for (int it = 0; it < 8; ++it) { int idx = tid + it*1024;
                int bi = idx >> 8, k = idx & 255;
                S[bi*256 + k] = cload(&rIn[bi*NR*NW + k]); }
            __syncthreads();
            float* gOut = pubG + (size_t)par*NBATCH*NG;
            #pragma unroll
            for (int bi = 0; bi < 32; ++bi) {
                const float4* RV4 = (const float4*)(S + bi*256);
                float a = acc[bi] + dot4(wrv, RV4[l]);
                a = wave_red(a);
                if (l == 0) cstore(&gOut[(size_t)bi*NG + r], a + bias);
            }
            post(&cG[g*16], (unsigned)(t+1), tid);
        }
    } else if (bid < 32 + 128 + 32) {
        // ========================= XI block (15 rows) =======================
        const int xg = bid - 160;
        const int row = xg*15 + wv;
        const bool act = (wv < 15) && (row < NXI);
        float4 xa0 = {0,0,0,0}, xa1 = {0,0,0,0}; float bias = 0.0f;
        if (act) {
            const float4* WX = (const float4*)(W_xi + (size_t)row*NH);
            xa0 = WX[l]; xa1 = WX[l+64]; bias = b_xi[row];
        }
        for (int t = 0; t < NT; ++t) {
            const int par = t & 1;
            wait_many(cSH, 32, (unsigned)(t+2), tid);    // h(t)
            const float* hIn = pubH + (size_t)par*NBATCH*NH;
            float* xOut = pubXI + (size_t)par*NBATCH*480;
            for (int p = 0; p < 4; ++p) {
                const int b0 = p*8;
                #pragma unroll
                for (int it = 0; it < 4; ++it) { int idx = tid + it*1024;
                    int bi = idx >> 9, k = idx & 511;
                    S[bi*512 + k] = cload(&hIn[(b0+bi)*NH + k]); }
                __syncthreads();
                if (act) {
                    #pragma unroll
                    for (int bi = 0; bi < 8; ++bi) {
                        const float4* H4 = (const float4*)(S + bi*512);
                        float a = dot4(xa0, H4[l]) + dot4(xa1, H4[l+64]);
                        a = wave_red(a);
                        if (l == 0) cstore(&xOut[(size_t)(b0+bi)*480 + row], a + bias);
                    }
                }
                __syncthreads();
            }
            post(&cX[xg*16], (unsigned)(t+1), tid);
        }
    } else {
        // ========================= OUT block (8 rows) =======================
        const int og = bid - 192;
        const int row = og*8 + wv;
        const bool act = (wv < 8);
        float4 o0 = {0,0,0,0}, o1 = {0,0,0,0}, o2 = {0,0,0,0}; float bias = 0.0f;
        if (act) {
            const float4* WO = (const float4*)(W_o + (size_t)row*NI);
            o0 = WO[l]; o1 = WO[l+64]; o2 = WO[128+l]; bias = b_o[row];
        }
        for (int t = 0; t < NT; ++t) {
            const int par = t & 1;
            wait_many(cSH, 32, (unsigned)(t+2), tid);    // h(t)
            wait_many(cSR, 32, (unsigned)(t+2), tid);    // rv(t)
            const float* hIn = pubH + (size_t)par*NBATCH*NH;
            const float* rIn = pubRV + (size_t)par*NBATCH*NR*NW;
            for (int p = 0; p < 4; ++p) {
                const int b0 = p*8;
                #pragma unroll
                for (int it = 0; it < 4; ++it) { int idx = tid + it*1024;
                    int bi = idx >> 9, k = idx & 511;
                    S[bi*768 + k] = cload(&hIn[(b0+bi)*NH + k]); }
                #pragma unroll
                for (int it = 0; it < 2; ++it) { int idx = tid + it*1024;
                    int bi = idx >> 8, k = idx & 255;
                    S[bi*768 + 512 + k] = cload(&rIn[(b0+bi)*NR*NW + k]); }
                __syncthreads();
                if (act) {
                    #pragma unroll
                    for (int bi = 0; bi < 8; ++bi) {
                        const float4* B4 = (const float4*)(S + bi*768);
                        float a = dot4(o0,B4[l]) + dot4(o1,B4[l+64]) + dot4(o2,B4[128+l]);
                        a = wave_red(a);
                        if (l == 0) out[((size_t)(b0+bi)*NT + t)*NH + row] = a + bias;
                    }
                }
                __syncthreads();
            }
            post(&cO[og*16], (unsigned)(t+1), tid);
        }
    }
}

extern "C" void kernel_launch(void* const* d_in, const int* in_sizes, int n_in,
                              void* d_out, int out_size, void* d_ws, size_t ws_size,
                              hipStream_t stream) {
    (void)in_sizes; (void)n_in; (void)out_size; (void)ws_size;
    const float* x    = (const float*)d_in[0];
    const float* W_ih = (const float*)d_in[1];
    const float* W_hh = (const float*)d_in[2];
    const float* b_ih = (const float*)d_in[3];
    const float* b_hh = (const float*)d_in[4];
    const float* W_xi = (const float*)d_in[5];
    const float* b_xi = (const float*)d_in[6];
    const float* W_o  = (const float*)d_in[7];
    const float* b_o  = (const float*)d_in[8];
    float* out = (float*)d_out;
    float* ws  = (float*)d_ws;

    dnc_zero<<<1, 1024, 0, stream>>>(ws);

    void* args[] = { (void*)&x, (void*)&W_ih, (void*)&W_hh, (void*)&b_ih,
                     (void*)&b_hh, (void*)&W_xi, (void*)&b_xi, (void*)&W_o,
                     (void*)&b_o, (void*)&out, (void*)&ws };
    hipLaunchCooperativeKernel((void*)dnc_pipe, dim3(NBLK), dim3(TPB),
                               args, 0, stream);
}

// Round 14
// 5498.543 us; speedup vs baseline: 2.2524x; 2.2524x over previous
//
#include <hip/hip_runtime.h>
#include <math.h>

#define TPB 1024
#define NBLK 256
#define NBATCH 32
#define NT 64
#define NH 512
#define NM 128
#define NR 4
#define NW 64
#define NI 768          // controller input size (H + R*W)
#define NXI 471         // interface vector size
#define NG 2048         // gate rows
#define EPSF 1e-6f
#define MS 65           // mem row stride (+1 pad)

// roles: [0,32) state | [32,160) gates(128) | [160,192) xi(32) | [192,256) out(64)

// ws layout (float offsets). pub* parity double-buffered.
#define WS_LINK  0                                 // [32][128*128]
#define WS_PUBH  (WS_LINK + NBATCH*NM*NM)          // [2][32][512]
#define WS_PUBRV (WS_PUBH + 2*NBATCH*NH)           // [2][32][256]
#define WS_PUBG  (WS_PUBRV + 2*NBATCH*NR*NW)       // [2][32][2048]
#define WS_PUBXI (WS_PUBG + 2*NBATCH*NG)           // [2][32][480]
#define WS_CNT   (WS_PUBXI + 2*NBATCH*480)         // 5 x 16-uint padded counters
// shared counters (uint offsets; one 64B line each) — r11-proven protocol
#define C_SH  0     // state h published:  32/step (+32 init)
#define C_SR  16    // state rv published: 32/step (+32 init)
#define C_G   32    // gates done: 128/step
#define C_X   48    // xi done: 32/step
#define C_O   64    // out done: 64/step
#define C_TOT 80

__device__ __forceinline__ float sigm(float x){ return 1.0f/(1.0f+expf(-x)); }
__device__ __forceinline__ float sftp(float x){ return fmaxf(x,0.0f)+log1pf(expf(-fabsf(x))); }
__device__ __forceinline__ float dot4(float4 a, float4 b){
    return a.x*b.x + a.y*b.y + a.z*b.z + a.w*b.w;
}
__device__ __forceinline__ float wave_red(float v){
    #pragma unroll
    for (int o = 32; o > 0; o >>= 1) v += __shfl_down(v, o);
    return v;
}
// LLC-coherent accessors (bypass L2, no invalidates) — proven r7-r11
__device__ __forceinline__ void cstore(float* p, float v){
    __hip_atomic_store(p, v, __ATOMIC_RELAXED, __HIP_MEMORY_SCOPE_AGENT);
}
__device__ __forceinline__ float cload(const float* p){
    return __hip_atomic_load(p, __ATOMIC_RELAXED, __HIP_MEMORY_SCOPE_AGENT);
}
// r11-proven: ONE thread polls ONE shared line (64B/poll, s_sleep backoff)
__device__ __forceinline__ void flag_sync_wait(unsigned int* c, unsigned int target,
                                               int tid){
    if (tid == 0) {
        while (__hip_atomic_load(c, __ATOMIC_RELAXED,
                                 __HIP_MEMORY_SCOPE_AGENT) < target)
            __builtin_amdgcn_s_sleep(2);
    }
    __syncthreads();
}
__device__ __forceinline__ void fbump(unsigned int* c, int tid){
    __syncthreads();   // drain all waves' stores first
    if (tid == 0)
        __hip_atomic_fetch_add(c, 1u, __ATOMIC_RELEASE,
                               __HIP_MEMORY_SCOPE_AGENT);
}

__global__ void dnc_zero(float* ws){
    unsigned int* z = (unsigned int*)(ws + WS_CNT);
    if (threadIdx.x < C_TOT) z[threadIdx.x] = 0u;
}

// ---- pooled LDS (floats) ----
#define O_MEM 0
#define O_H   8320
#define O_C   8832
#define O_RW  9344
#define O_WWO 9856
#define O_WWN 9984
#define O_USG 10112
#define O_PRC 10240
#define O_XI  10368
#define O_KEY 10840
#define O_WK  11096
#define O_ER  11160
#define O_WV  11224
#define O_RS  11288
#define O_FG  11292
#define O_MD  11296
#define O_NK  11308
#define O_SC  11312
#define O_NMO 11320
#define O_NMN 11448
#define O_WCW 11576
#define O_UU  11704
#define O_SU  11832
#define O_CUM 11960
#define O_RNK 12088
#define O_CCW 12216
#define O_FWD 12728
#define O_RV  13240
#define O_RED 13496
#define S_SZ  13504
// gates role: staging S[0..8191], accS at 8192..8703 (disjoint role, safe)
#define O_ACC 8192

__global__ __launch_bounds__(TPB) void dnc_pipe2(
    const float* __restrict__ x, const float* __restrict__ W_ih,
    const float* __restrict__ W_hh, const float* __restrict__ b_ih,
    const float* __restrict__ b_hh, const float* __restrict__ W_xi,
    const float* __restrict__ b_xi, const float* __restrict__ W_o,
    const float* __restrict__ b_o, float* __restrict__ out,
    float* __restrict__ ws)
{
    __shared__ __align__(16) float S[S_SZ];

    const int tid = threadIdx.x;
    const int wv  = tid >> 6;
    const int l   = tid & 63;
    const int bid = blockIdx.x;

    float* __restrict__ pubH  = ws + WS_PUBH;
    float* __restrict__ pubRV = ws + WS_PUBRV;
    float* __restrict__ pubG  = ws + WS_PUBG;
    float* __restrict__ pubXI = ws + WS_PUBXI;
    unsigned int* __restrict__ CNT = (unsigned int*)(ws + WS_CNT);

    if (bid < NBATCH) {
        // ========================= STATE block =========================
        const int b = bid;
        float* __restrict__ lk = ws + WS_LINK + (size_t)b*NM*NM;
        float* mem = S+O_MEM;  float* hS = S+O_H;   float* cS = S+O_C;
        float* rwS = S+O_RW;   float* wwO = S+O_WWO; float* wwN = S+O_WWN;
        float* usg = S+O_USG;  float* prc = S+O_PRC; float* xiS = S+O_XI;
        float* keys = S+O_KEY; float* wkey = S+O_WK; float* ers = S+O_ER;
        float* wvec = S+O_WV;  float* rstr = S+O_RS; float* fgte = S+O_FG;
        float* modes = S+O_MD; float* nkey = S+O_NK; float* sc = S+O_SC;
        float* nmo = S+O_NMO;  float* nmn = S+O_NMN; float* wcw = S+O_WCW;
        float* uu = S+O_UU;    float* su = S+O_SU;   float* cum = S+O_CUM;
        int*   rnk = (int*)(S+O_RNK);
        float* ccw = S+O_CCW;  float* fwdT = S+O_FWD; float* rv = S+O_RV;
        float* red = S+O_RED;

        for (int e = tid; e < NM*NM; e += TPB) lk[e] = 0.0f;
        for (int e = tid; e < NM*NW; e += TPB) mem[(e>>6)*MS + (e&63)] = EPSF;
        for (int e = tid; e < NH; e += TPB){ hS[e]=0.0f; cS[e]=0.0f; }
        for (int e = tid; e < NR*NM; e += TPB) rwS[e]=0.0f;
        for (int e = tid; e < NM; e += TPB){ wwO[e]=0.0f; usg[e]=0.0f; prc[e]=0.0f; }
        // publish h_{-1}=0, rv_{-1}=0 into parity 1 (gates step 0 reads parity 1)
        if (tid < NH)    cstore(&pubH[(size_t)1*NBATCH*NH + b*NH + tid], 0.0f);
        if (tid < NR*NW) cstore(&pubRV[(size_t)1*NBATCH*NR*NW + b*NR*NW + tid], 0.0f);
        fbump(&CNT[C_SH], tid);
        fbump(&CNT[C_SR], tid);

        for (int t = 0; t < NT; ++t) {
            const int par = t & 1;
            // gates(t) ready
            flag_sync_wait(&CNT[C_G], 128u*(unsigned)(t+1), tid);
            {
                const float* gb = pubG + ((size_t)par*NBATCH + b)*NG;
                if (tid < NH) {
                    float ig = sigm(cload(&gb[tid]));
                    float fg = sigm(cload(&gb[NH + tid]));
                    float gg = tanhf(cload(&gb[2*NH + tid]));
                    float og = sigm(cload(&gb[3*NH + tid]));
                    float c = fg*cS[tid] + ig*gg;
                    cS[tid] = c;
                    hS[tid] = og*tanhf(c);
                }
            }
            __syncthreads();
            // out(t-2) done before overwriting its h/rv parity
            if (t >= 2) flag_sync_wait(&CNT[C_O], 64u*(unsigned)(t-1), tid);
            if (tid < NH) cstore(&pubH[(size_t)par*NBATCH*NH + b*NH + tid], hS[tid]);
            fbump(&CNT[C_SH], tid);

            // nmo — no xi dependency; overlaps xi compute
            #pragma unroll
            for (int ri = 0; ri < 8; ++ri) {
                int row = wv*8 + ri;
                float v = mem[row*MS + l];
                float s2 = wave_red(v*v);
                if (l == 0) nmo[row] = sqrtf(s2);
            }
            __syncthreads();

            // xi(t) ready
            flag_sync_wait(&CNT[C_X], 32u*(unsigned)(t+1), tid);
            if (tid < NXI) xiS[tid] = cload(&pubXI[(size_t)par*NBATCH*480 + b*480 + tid]);
            __syncthreads();

            // E1: unpack interface
            if (tid < 256)       keys[tid] = tanhf(xiS[tid]);
            else if (tid < 260)  rstr[tid-256] = sftp(xiS[tid]);
            else if (tid < 324)  wkey[tid-260] = tanhf(xiS[tid]);
            else if (tid == 324) sc[0] = sftp(xiS[324]);
            else if (tid < 389)  ers[tid-325] = sigm(xiS[tid]);
            else if (tid < 453)  wvec[tid-389] = tanhf(xiS[tid]);
            else if (tid < 457)  fgte[tid-453] = sigm(xiS[tid]);
            else if (tid == 457) sc[1] = sigm(xiS[457]);
            else if (tid == 458) sc[2] = sigm(xiS[458]);
            else if (tid < 463) {
                int r = tid - 459;
                float a0=xiS[459+3*r], a1=xiS[460+3*r], a2=xiS[461+3*r];
                float mx = fmaxf(a0, fmaxf(a1, a2));
                float e0=expf(a0-mx), e1=expf(a1-mx), e2=expf(a2-mx);
                float si = 1.0f/(e0+e1+e2);
                modes[3*r]=e0*si; modes[3*r+1]=e1*si; modes[3*r+2]=e2*si;
            }
            __syncthreads();

            // E2a: key norms
            if (tid < NR) {
                float ssum = 0.0f;
                for (int w = 0; w < NW; ++w) { float v = keys[tid*NW+w]; ssum += v*v; }
                nkey[tid] = sqrtf(ssum);
            } else if (tid == NR) {
                float ssum = 0.0f;
                for (int w = 0; w < NW; ++w) { float v = wkey[w]; ssum += v*v; }
                sc[3] = sqrtf(ssum);
            }
            // E2b: usage + uu (fused)
            if (tid >= 64 && tid < 64+NM) {
                int m = tid - 64;
                float u = usg[m];
                u = u + (1.0f - u)*wwO[m];
                float psi = 1.0f;
                #pragma unroll
                for (int r = 0; r < NR; ++r) psi *= (1.0f - fgte[r]*rwS[r*NM+m]);
                u *= psi;
                usg[m] = u;
                uu[m] = 5e-6f + (1.0f - 5e-6f)*u;
            }
            __syncthreads();

            // F1: write-content logits
            if (tid < NM) {
                float d = 0.0f;
                for (int w = 0; w < NW; ++w) d += wkey[w]*mem[tid*MS+w];
                wcw[tid] = d/(sc[3]*nmo[tid] + EPSF) * sc[0];
            }
            __syncthreads();
            // F2: softmax over 128
            if (tid < 64) {
                float v = fmaxf(wcw[tid], wcw[tid+64]);
                #pragma unroll
                for (int o = 32; o > 0; o >>= 1) v = fmaxf(v, __shfl_down(v, o));
                if (tid == 0) red[0] = v;
            }
            __syncthreads();
            if (tid < NM) wcw[tid] = expf(wcw[tid] - red[0]);
            __syncthreads();
            if (tid < 64) {
                float v = wave_red(wcw[tid] + wcw[tid+64]);
                if (tid == 0) red[0] = 1.0f/v;
            }
            __syncthreads();
            if (tid < NM) wcw[tid] *= red[0];
            __syncthreads();

            // G2: stable rank
            if (tid < NM) {
                float um = uu[tid]; int rk = 0;
                for (int j = 0; j < NM; ++j) {
                    float uj = uu[j];
                    rk += (uj < um) || (uj == um && j < tid);
                }
                rnk[tid] = rk;
                su[rk] = um;
            }
            __syncthreads();
            // G3: product scan (wave 0)
            if (tid < 64) {
                float a = su[tid], bb = su[64+tid];
                #pragma unroll
                for (int o = 1; o < 64; o <<= 1) {
                    float ta = __shfl_up(a, o);
                    float tb = __shfl_up(bb, o);
                    if (tid >= o) { a *= ta; bb *= tb; }
                }
                float P0 = __shfl(a, 63);
                cum[tid] = a;
                cum[64+tid] = P0*bb;
            }
            __syncthreads();
            // G4: alloc + write weighting
            if (tid < NM) {
                int rk = rnk[tid];
                float excl = (rk == 0) ? 1.0f : cum[rk-1];
                float al = (1.0f - uu[tid])*excl;
                wwN[tid] = sc[2]*(sc[1]*al + (1.0f - sc[1])*wcw[tid]);
            }
            __syncthreads();
            // G5: sum(wwN)
            if (tid < 64) {
                float v = wave_red(wwN[tid] + wwN[tid+64]);
                if (tid == 0) sc[4] = v;
            }
            __syncthreads();

            // H (fused): mem erase/write + new norms + link
            #pragma unroll
            for (int ri = 0; ri < 8; ++ri) {
                int row = wv*8 + ri;
                float wm = wwN[row];
                float v = mem[row*MS + l];
                float nv = v*(1.0f - wm*ers[l]) + wm*wvec[l];
                mem[row*MS + l] = nv;
                float s2 = wave_red(nv*nv);
                if (l == 0) nmn[row] = sqrtf(s2);
            }
            for (int e = tid; e < NM*NM; e += TPB) {
                int i = e >> 7, j = e & 127;
                float nl = (i == j) ? 0.0f
                         : (1.0f - wwN[i] - wwN[j])*lk[e] + wwN[i]*prc[j];
                lk[e] = nl;
            }
            __syncthreads();
            // H3: precedence
            if (tid < NM) prc[tid] = (1.0f - sc[4])*prc[tid] + wwN[tid];
            __syncthreads();

            // I: read-content logits + per-r softmax
            if (tid < NR*NM) {
                int r = tid >> 7, m = tid & 127;
                float d = 0.0f;
                for (int w = 0; w < NW; ++w) d += keys[r*NW+w]*mem[m*MS+w];
                ccw[tid] = d/(nkey[r]*nmn[m] + EPSF) * rstr[r];
            }
            __syncthreads();
            if (tid < 256) {
                int r = tid >> 6, ll = tid & 63;
                float v = fmaxf(ccw[r*NM+ll], ccw[r*NM+ll+64]);
                #pragma unroll
                for (int o = 32; o > 0; o >>= 1) v = fmaxf(v, __shfl_down(v, o));
                if (ll == 0) red[r] = v;
            }
            __syncthreads();
            if (tid < NR*NM) ccw[tid] = expf(ccw[tid] - red[tid>>7]);
            __syncthreads();
            if (tid < 256) {
                int r = tid >> 6, ll = tid & 63;
                float v = wave_red(ccw[r*NM+ll] + ccw[r*NM+ll+64]);
                if (ll == 0) red[4+r] = 1.0f/v;
            }
            __syncthreads();
            if (tid < NR*NM) ccw[tid] *= red[4+(tid>>7)];
            __syncthreads();

            // J1: fwd[r][m]
            {
                const int p0 = wv*32;
                for (int i = 0; i < 32; ++i) {
                    const int p = p0 + i, r = p >> 7, m = p & 127;
                    float partial = lk[m*NM + l]*rwS[r*NM + l]
                                  + lk[m*NM + 64 + l]*rwS[r*NM + 64 + l];
                    partial = wave_red(partial);
                    if (l == 0) fwdT[p] = partial;
                }
            }
            __syncthreads();
            // J2: bwd + mode mix
            float rwnew = 0.0f;
            if (tid < NR*NM) {
                int r = tid >> 7, m = tid & 127;
                float bw = 0.0f;
                for (int i = 0; i < NM; ++i) bw += lk[i*NM+m]*rwS[r*NM+i];
                rwnew = modes[3*r]*bw + modes[3*r+1]*fwdT[tid] + modes[3*r+2]*ccw[tid];
            }
            __syncthreads();
            if (tid < NR*NM) rwS[tid] = rwnew;
            __syncthreads();

            // K: read vectors + publish rv
            if (tid < NR*NW) {
                int r = tid >> 6, w = tid & 63;
                float ssum = 0.0f;
                for (int m = 0; m < NM; ++m) ssum += rwS[r*NM+m]*mem[m*MS+w];
                rv[tid] = ssum;
                cstore(&pubRV[(size_t)par*NBATCH*NR*NW + b*NR*NW + tid], ssum);
            }
            fbump(&CNT[C_SR], tid);

            if (tid < NM) wwO[tid] = wwN[tid];
            __syncthreads();
        }
    } else if (bid < 32 + 128) {
        // ========================= GATES block (16 rows) ====================
        const int g = bid - 32;
        const int r = g*16 + wv;
        const float4* WA = (const float4*)(W_ih + (size_t)r*NI);
        float4 wx0 = WA[l], wx1 = WA[l+64], wrv = WA[128+l];
        const float4* WB = (const float4*)(W_hh + (size_t)r*NH);
        float4 wh0 = WB[l], wh1 = WB[l+64];
        const float bias = b_ih[r] + b_hh[r];
        float* accS = S + O_ACC;   // [16 waves][32 batches] early partials (LDS!)

        for (int t = 0; t < NT; ++t) {
            const int par = t & 1, parp = (t+1) & 1;   // parp = parity of t-1
            // EARLY: x(t) + h(t-1) — overlaps state machinery of step t-1
            flag_sync_wait(&CNT[C_SH], 32u*(unsigned)(t+1), tid);
            const float* hIn = pubH + (size_t)parp*NBATCH*NH;
            for (int p = 0; p < 4; ++p) {
                const int b0 = p*8;
                // x: 8 batches x 512 -> S[0..4095]
                #pragma unroll
                for (int it = 0; it < 4; ++it) { int idx = tid + it*1024;
                    int bi = idx >> 9, k = idx & 511;
                    S[bi*512 + k] = x[((size_t)(b0+bi)*NT + t)*NH + k]; }
                // h: 8 batches x 512 -> S[4096..8191]
                #pragma unroll
                for (int it = 0; it < 4; ++it) { int idx = tid + it*1024;
                    int bi = idx >> 9, k = idx & 511;
                    S[4096 + bi*512 + k] = cload(&hIn[(b0+bi)*NH + k]); }
                __syncthreads();
                #pragma unroll
                for (int bi = 0; bi < 8; ++bi) {
                    const float4* X4 = (const float4*)(S + bi*512);
                    const float4* H4 = (const float4*)(S + 4096 + bi*512);
                    float a = dot4(wx0, X4[l]) + dot4(wx1, X4[l+64])
                            + dot4(wh0, H4[l]) + dot4(wh1, H4[l+64]);
                    a = wave_red(a);
                    if (l == 0) accS[wv*32 + b0 + bi] = a;   // LDS, no VGPR array
                }
                __syncthreads();
            }
            // LATE: rv(t-1) — the only critical-path part
            flag_sync_wait(&CNT[C_SR], 32u*(unsigned)(t+1), tid);
            const float* rIn = pubRV + (size_t)parp*NBATCH*NR*NW;
            #pragma unroll
            for (int it = 0; it < 8; ++it) { int idx = tid + it*1024;
                int bi = idx >> 8, k = idx & 255;
                S[bi*256 + k] = cload(&rIn[bi*NR*NW + k]); }
            __syncthreads();
            float* gOut = pubG + (size_t)par*NBATCH*NG;
            #pragma unroll
            for (int bi = 0; bi < 32; ++bi) {
                const float4* RV4 = (const float4*)(S + bi*256);
                float d = dot4(wrv, RV4[l]);
                d = wave_red(d);
                if (l == 0) cstore(&gOut[(size_t)bi*NG + r],
                                   d + accS[wv*32 + bi] + bias);
            }
            fbump(&CNT[C_G], tid);
        }
    } else if (bid < 32 + 128 + 32) {
        // ========================= XI block (15 rows) =======================
        const int xg = bid - 160;
        const int row = xg*15 + wv;
        const bool act = (wv < 15) && (row < NXI);
        float4 xa0 = {0,0,0,0}, xa1 = {0,0,0,0}; float bias = 0.0f;
        if (act) {
            const float4* WX = (const float4*)(W_xi + (size_t)row*NH);
            xa0 = WX[l]; xa1 = WX[l+64]; bias = b_xi[row];
        }
        for (int t = 0; t < NT; ++t) {
            const int par = t & 1;
            flag_sync_wait(&CNT[C_SH], 32u*(unsigned)(t+2), tid);   // h(t)
            const float* hIn = pubH + (size_t)par*NBATCH*NH;
            float* xOut = pubXI + (size_t)par*NBATCH*480;
            for (int p = 0; p < 4; ++p) {
                const int b0 = p*8;
                #pragma unroll
                for (int it = 0; it < 4; ++it) { int idx = tid + it*1024;
                    int bi = idx >> 9, k = idx & 511;
                    S[bi*512 + k] = cload(&hIn[(b0+bi)*NH + k]); }
                __syncthreads();
                if (act) {
                    #pragma unroll
                    for (int bi = 0; bi < 8; ++bi) {
                        const float4* H4 = (const float4*)(S + bi*512);
                        float a = dot4(xa0, H4[l]) + dot4(xa1, H4[l+64]);
                        a = wave_red(a);
                        if (l == 0) cstore(&xOut[(size_t)(b0+bi)*480 + row], a + bias);
                    }
                }
                __syncthreads();
            }
            fbump(&CNT[C_X], tid);
        }
    } else {
        // ========================= OUT block (8 rows) =======================
        const int og = bid - 192;
        const int row = og*8 + wv;
        const bool act = (wv < 8);
        float4 o0 = {0,0,0,0}, o1 = {0,0,0,0}, o2 = {0,0,0,0}; float bias = 0.0f;
        if (act) {
            const float4* WO = (const float4*)(W_o + (size_t)row*NI);
            o0 = WO[l]; o1 = WO[l+64]; o2 = WO[128+l]; bias = b_o[row];
        }
        for (int t = 0; t < NT; ++t) {
            const int par = t & 1;
            flag_sync_wait(&CNT[C_SH], 32u*(unsigned)(t+2), tid);   // h(t)
            flag_sync_wait(&CNT[C_SR], 32u*(unsigned)(t+2), tid);   // rv(t)
            const float* hIn = pubH + (size_t)par*NBATCH*NH;
            const float* rIn = pubRV + (size_t)par*NBATCH*NR*NW;
            for (int p = 0; p < 4; ++p) {
                const int b0 = p*8;
                #pragma unroll
                for (int it = 0; it < 4; ++it) { int idx = tid + it*1024;
                    int bi = idx >> 9, k = idx & 511;
                    S[bi*768 + k] = cload(&hIn[(b0+bi)*NH + k]); }
                #pragma unroll
                for (int it = 0; it < 2; ++it) { int idx = tid + it*1024;
                    int bi = idx >> 8, k = idx & 255;
                    S[bi*768 + 512 + k] = cload(&rIn[(b0+bi)*NR*NW + k]); }
                __syncthreads();
                if (act) {
                    #pragma unroll
                    for (int bi = 0; bi < 8; ++bi) {
                        const float4* B4 = (const float4*)(S + bi*768);
                        float a = dot4(o0,B4[l]) + dot4(o1,B4[l+64]) + dot4(o2,B4[128+l]);
                        a = wave_red(a);
                        if (l == 0) out[((size_t)(b0+bi)*NT + t)*NH + row] = a + bias;
                    }
                }
                __syncthreads();
            }
            fbump(&CNT[C_O], tid);
        }
    }
}

extern "C" void kernel_launch(void* const* d_in, const int* in_sizes, int n_in,
                              void* d_out, int out_size, void* d_ws, size_t ws_size,
                              hipStream_t stream) {
    (void)in_sizes; (void)n_in; (void)out_size; (void)ws_size;
    const float* x    = (const float*)d_in[0];
    const float* W_ih = (const float*)d_in[1];
    const float* W_hh = (const float*)d_in[2];
    const float* b_ih = (const float*)d_in[3];
    const float* b_hh = (const float*)d_in[4];
    const float* W_xi = (const float*)d_in[5];
    const float* b_xi = (const float*)d_in[6];
    const float* W_o  = (const float*)d_in[7];
    const float* b_o  = (const float*)d_in[8];
    float* out = (float*)d_out;
    float* ws  = (float*)d_ws;

    dnc_zero<<<1, 256, 0, stream>>>(ws);

    void* args[] = { (void*)&x, (void*)&W_ih, (void*)&W_hh, (void*)&b_ih,
                     (void*)&b_hh, (void*)&W_xi, (void*)&b_xi, (void*)&W_o,
                     (void*)&b_o, (void*)&out, (void*)&ws };
    hipLaunchCooperativeKernel((void*)dnc_pipe2, dim3(NBLK), dim3(TPB),
                               args, 0, stream);
}